// Round 1
// baseline (763.012 us; speedup 1.0000x reference)
//
#include <hip/hip_runtime.h>

#define NN 50000
#define NE 600000
#define DD 128
#define NH 4

// ---------- float atomic-max via monotonic uint encoding (exact, order-independent) ----------
__device__ __forceinline__ unsigned encf(float f) {
  unsigned u = __float_as_uint(f);
  return (u & 0x80000000u) ? ~u : (u | 0x80000000u);
}
__device__ __forceinline__ float decf(unsigned k) {
  return (k & 0x80000000u) ? __uint_as_float(k & 0x7fffffffu) : __uint_as_float(~k);
}

// ---------- CSR build ----------
__global__ void count_deg(const int* __restrict__ ei, int* __restrict__ deg) {
  int e = blockIdx.x * 256 + threadIdx.x;
  if (e < NE) atomicAdd(deg + ei[NE + e], 1);
}

__global__ void scan_deg(const int* __restrict__ deg, int* __restrict__ rowp) {
  __shared__ int buf[1024];
  __shared__ int carry;
  int t = threadIdx.x;
  if (t == 0) carry = 0;
  __syncthreads();
  for (int base = 0; base < NN; base += 1024) {
    int i = base + t;
    int v = (i < NN) ? deg[i] : 0;
    buf[t] = v;
    __syncthreads();
    for (int o = 1; o < 1024; o <<= 1) {
      int add = (t >= o) ? buf[t - o] : 0;
      __syncthreads();
      buf[t] += add;
      __syncthreads();
    }
    int incl = buf[t];
    if (i < NN) rowp[i] = carry + incl - v;  // exclusive scan + chunk carry
    __syncthreads();
    if (t == 1023) carry += incl;
    __syncthreads();
  }
  if (t == 0) rowp[NN] = carry;
}

__global__ void scatter_edges(const int* __restrict__ ei, const int* __restrict__ rowp,
                              int* __restrict__ cur, int* __restrict__ col) {
  int e = blockIdx.x * 256 + threadIdx.x;
  if (e < NE) {
    int d = ei[NE + e];
    int p = atomicAdd(cur + d, 1);
    col[rowp[d] + p] = e;
  }
}

// ---------- fused dual GEMM: xl = h@Wl+bl, xr = h@Wr+br ----------
// block 256 threads, tile 32 rows x 256 cols (128 xl + 128 xr), K tiled by 32.
__global__ __launch_bounds__(256) void dual_gemm(
    const float* __restrict__ h, const float* __restrict__ Wl,
    const float* __restrict__ blv, const float* __restrict__ Wr,
    const float* __restrict__ brv, float* __restrict__ xl, float* __restrict__ xr) {
  __shared__ __align__(16) float Wt[32][256];
  __shared__ __align__(16) float Ht[32][36];  // padded stride 36 (144B, 16B-aligned rows)
  const int t = threadIdx.x;
  const int row0 = blockIdx.x * 32;
  const int ct = t & 31;   // col group: cols ct*4..ct*4+3 (and +128)
  const int rt = t >> 5;   // row group: rows rt*4..rt*4+3
  float acc[4][8];
#pragma unroll
  for (int i = 0; i < 4; i++)
#pragma unroll
    for (int j = 0; j < 8; j++) acc[i][j] = 0.f;

  const int hr = t >> 3;          // 0..31 (row within tile for H staging)
  const int hk = (t & 7) << 2;    // 0,4,...,28

  for (int k0 = 0; k0 < 128; k0 += 32) {
    // stage W tile [32][256] (Wl cols 0..127, Wr cols 128..255)
#pragma unroll
    for (int j = 0; j < 8; j++) {
      int f4 = t + 256 * j;          // 0..2047 float4 slots
      int k = f4 >> 6;               // 64 float4 per k-row
      int c4 = (f4 & 63) << 2;
      float4 v;
      if (c4 < 128) v = *(const float4*)(Wl + (size_t)(k0 + k) * 128 + c4);
      else          v = *(const float4*)(Wr + (size_t)(k0 + k) * 128 + (c4 - 128));
      *(float4*)(&Wt[k][c4]) = v;
    }
    // stage H tile transposed
    float4 hv4 = make_float4(0.f, 0.f, 0.f, 0.f);
    if (row0 + hr < NN) hv4 = *(const float4*)(h + (size_t)(row0 + hr) * DD + k0 + hk);
    Ht[hk + 0][hr] = hv4.x; Ht[hk + 1][hr] = hv4.y;
    Ht[hk + 2][hr] = hv4.z; Ht[hk + 3][hr] = hv4.w;
    __syncthreads();
#pragma unroll
    for (int k = 0; k < 32; k++) {
      float4 w0 = *(const float4*)(&Wt[k][ct << 2]);
      float4 w1 = *(const float4*)(&Wt[k][128 + (ct << 2)]);
      float4 hv = *(const float4*)(&Ht[k][rt << 2]);
      float hs[4] = {hv.x, hv.y, hv.z, hv.w};
#pragma unroll
      for (int i = 0; i < 4; i++) {
        acc[i][0] += hs[i] * w0.x; acc[i][1] += hs[i] * w0.y;
        acc[i][2] += hs[i] * w0.z; acc[i][3] += hs[i] * w0.w;
        acc[i][4] += hs[i] * w1.x; acc[i][5] += hs[i] * w1.y;
        acc[i][6] += hs[i] * w1.z; acc[i][7] += hs[i] * w1.w;
      }
    }
    __syncthreads();
  }
  float4 bl4 = *(const float4*)(blv + (ct << 2));
  float4 br4 = *(const float4*)(brv + (ct << 2));
#pragma unroll
  for (int i = 0; i < 4; i++) {
    int row = row0 + (rt << 2) + i;
    if (row < NN) {
      float4 o0 = make_float4(acc[i][0] + bl4.x, acc[i][1] + bl4.y,
                              acc[i][2] + bl4.z, acc[i][3] + bl4.w);
      float4 o1 = make_float4(acc[i][4] + br4.x, acc[i][5] + br4.y,
                              acc[i][6] + br4.z, acc[i][7] + br4.w);
      *(float4*)(xl + (size_t)row * DD + (ct << 2)) = o0;
      *(float4*)(xr + (size_t)row * DD + (ct << 2)) = o1;
    }
  }
}

// ---------- softmax state init ----------
__global__ void init_mden(unsigned* __restrict__ menc, float* __restrict__ den) {
  int i = blockIdx.x * 256 + threadIdx.x;
  if (i < NN * NH) { menc[i] = 0x007fffffu; /* enc(-inf) */ den[i] = 0.f; }
}

// ---------- per-edge attention scores + segment max (one wave per edge) ----------
__global__ __launch_bounds__(256) void edge_score(
    const int* __restrict__ ei, const float* __restrict__ xl,
    const float* __restrict__ xr, const float* __restrict__ att,
    float* __restrict__ score, unsigned* __restrict__ menc) {
  int wid = (blockIdx.x * 256 + threadIdx.x) >> 6;  // edge id
  if (wid >= NE) return;
  int lane = threadIdx.x & 63;
  int s = ei[wid];
  int d = ei[NE + wid];
  int c = lane << 1;
  float2 a = *(const float2*)(xl + (size_t)s * DD + c);
  float2 b = *(const float2*)(xr + (size_t)d * DD + c);
  float vx = a.x + b.x, vy = a.y + b.y;
  vx = vx > 0.f ? vx : 0.2f * vx;   // leaky_relu, NEG=0.2
  vy = vy > 0.f ? vy : 0.2f * vy;
  float2 at = *(const float2*)(att + c);
  float p = vx * at.x + vy * at.y;
  p += __shfl_xor(p, 1);
  p += __shfl_xor(p, 2);
  p += __shfl_xor(p, 4);
  p += __shfl_xor(p, 8);           // reduce within 16-lane head group
  if ((lane & 15) == 0) {
    int hh = lane >> 4;
    score[(size_t)wid * NH + hh] = p;
    atomicMax(menc + (size_t)d * NH + hh, encf(p));
  }
}

// ---------- exp(score - m) + denominator ----------
__global__ void exp_den(const int* __restrict__ ei, float* __restrict__ score,
                        const unsigned* __restrict__ menc, float* __restrict__ den) {
  int idx = blockIdx.x * 256 + threadIdx.x;
  if (idx >= NE * NH) return;
  int e = idx >> 2;
  int hh = idx & 3;
  int d = ei[NE + e];
  float mm = decf(menc[d * NH + hh]);
  float ex = expf(score[idx] - mm);
  score[idx] = ex;  // overwrite score with exp value
  atomicAdd(den + d * NH + hh, ex);
}

// ---------- aggregation + bias + LayerNorm + ELU (one wave per dst node) ----------
__global__ __launch_bounds__(256) void aggregate(
    const int* __restrict__ ei, const int* __restrict__ rowp,
    const int* __restrict__ col, const float* __restrict__ score,
    const float* __restrict__ den, const float* __restrict__ xl,
    const float* __restrict__ bias, const float* __restrict__ gam,
    const float* __restrict__ bet, float* __restrict__ out) {
  int node = (blockIdx.x * 256 + threadIdx.x) >> 6;
  if (node >= NN) return;
  int lane = threadIdx.x & 63;
  int hh = lane >> 4;              // head of dims 2*lane, 2*lane+1
  int c = lane << 1;
  float inv = 1.f / (den[node * NH + hh] + 1e-16f);
  int j0 = rowp[node], j1 = rowp[node + 1];
  float ax = 0.f, ay = 0.f;
  for (int j = j0; j < j1; j++) {
    int e = col[j];
    int s = ei[e];
    float alpha = score[(size_t)e * NH + hh] * inv;
    float2 xv = *(const float2*)(xl + (size_t)s * DD + c);
    ax += alpha * xv.x; ay += alpha * xv.y;
  }
  float vx = ax + bias[c], vy = ay + bias[c + 1];
  float s1 = vx + vy, s2 = vx * vx + vy * vy;
#pragma unroll
  for (int o = 1; o < 64; o <<= 1) { s1 += __shfl_xor(s1, o); s2 += __shfl_xor(s2, o); }
  float mean = s1 * (1.f / 128.f);
  float var = s2 * (1.f / 128.f) - mean * mean;
  float rstd = rsqrtf(var + 1e-5f);
  float nx = (vx - mean) * rstd * gam[c] + bet[c];
  float ny = (vy - mean) * rstd * gam[c + 1] + bet[c + 1];
  out[(size_t)node * DD + c]     = nx > 0.f ? nx : expf(nx) - 1.f;
  out[(size_t)node * DD + c + 1] = ny > 0.f ? ny : expf(ny) - 1.f;
}

extern "C" void kernel_launch(void* const* d_in, const int* in_sizes, int n_in,
                              void* d_out, int out_size, void* d_ws, size_t ws_size,
                              hipStream_t stream) {
  const float* x  = (const float*)d_in[0];
  const int*   ei = (const int*)d_in[1];
  const float* Wl[2]   = {(const float*)d_in[2],  (const float*)d_in[10]};
  const float* bl[2]   = {(const float*)d_in[3],  (const float*)d_in[11]};
  const float* Wr[2]   = {(const float*)d_in[4],  (const float*)d_in[12]};
  const float* br[2]   = {(const float*)d_in[5],  (const float*)d_in[13]};
  const float* att[2]  = {(const float*)d_in[6],  (const float*)d_in[14]};
  const float* bias[2] = {(const float*)d_in[7],  (const float*)d_in[15]};
  const float* gam[2]  = {(const float*)d_in[8],  (const float*)d_in[16]};
  const float* bet[2]  = {(const float*)d_in[9],  (const float*)d_in[17]};
  float* out = (float*)d_out;

  char* w = (char*)d_ws;
  auto carve = [&](size_t bytes) {
    char* p = w;
    w += (bytes + 255) & ~(size_t)255;
    return p;
  };
  float*    xl    = (float*)carve((size_t)NN * DD * 4);
  float*    xr    = (float*)carve((size_t)NN * DD * 4);
  float*    score = (float*)carve((size_t)NE * NH * 4);
  unsigned* menc  = (unsigned*)carve((size_t)NN * NH * 4);
  float*    den   = (float*)carve((size_t)NN * NH * 4);
  int*      deg   = (int*)carve((size_t)NN * 4);
  int*      cur   = (int*)carve((size_t)NN * 4);
  int*      rowp  = (int*)carve((size_t)(NN + 1) * 4);
  int*      col   = (int*)carve((size_t)NE * 4);
  float*    hmid  = (float*)carve((size_t)NN * DD * 4);

  // CSR build (recomputed every call — deterministic, no cross-call state)
  hipMemsetAsync(deg, 0, (size_t)NN * 4, stream);
  hipMemsetAsync(cur, 0, (size_t)NN * 4, stream);
  count_deg<<<(NE + 255) / 256, 256, 0, stream>>>(ei, deg);
  scan_deg<<<1, 1024, 0, stream>>>(deg, rowp);
  scatter_edges<<<(NE + 255) / 256, 256, 0, stream>>>(ei, rowp, cur, col);

  for (int l = 0; l < 2; l++) {
    const float* hin = l ? hmid : x;
    float* hout = l ? out : hmid;
    dual_gemm<<<(NN + 31) / 32, 256, 0, stream>>>(hin, Wl[l], bl[l], Wr[l], br[l], xl, xr);
    init_mden<<<(NN * NH + 255) / 256, 256, 0, stream>>>(menc, den);
    edge_score<<<NE / 4, 256, 0, stream>>>(ei, xl, xr, att[l], score, menc);
    exp_den<<<(NE * NH + 255) / 256, 256, 0, stream>>>(ei, score, menc, den);
    aggregate<<<(NN * 64 + 255) / 256, 256, 0, stream>>>(ei, rowp, col, score, den, xl,
                                                         bias[l], gam[l], bet[l], hout);
  }
}

// Round 5
// 440.251 us; speedup vs baseline: 1.7331x; 1.7331x over previous
//
#include <hip/hip_runtime.h>

#define NN 50000
#define NE 600000
#define DD 128
#define NH 4

// ---------- CSR build ----------
__global__ void count_deg(const int* __restrict__ ei, int* __restrict__ deg) {
  int e = blockIdx.x * 256 + threadIdx.x;
  if (e < NE) atomicAdd(deg + ei[NE + e], 1);
}

__global__ void scan_deg(const int* __restrict__ deg, int* __restrict__ rowp) {
  __shared__ int buf[1024];
  __shared__ int carry;
  int t = threadIdx.x;
  if (t == 0) carry = 0;
  __syncthreads();
  for (int base = 0; base < NN; base += 1024) {
    int i = base + t;
    int v = (i < NN) ? deg[i] : 0;
    buf[t] = v;
    __syncthreads();
    for (int o = 1; o < 1024; o <<= 1) {
      int add = (t >= o) ? buf[t - o] : 0;
      __syncthreads();
      buf[t] += add;
      __syncthreads();
    }
    int incl = buf[t];
    if (i < NN) rowp[i] = carry + incl - v;  // exclusive scan + chunk carry
    __syncthreads();
    if (t == 1023) carry += incl;
    __syncthreads();
  }
  if (t == 0) rowp[NN] = carry;
}

// store SOURCE node id directly (no edge-id indirection needed anymore)
__global__ void scatter_src(const int* __restrict__ ei, const int* __restrict__ rowp,
                            int* __restrict__ cur, int* __restrict__ colsrc) {
  int e = blockIdx.x * 256 + threadIdx.x;
  if (e < NE) {
    int d = ei[NE + e];
    int p = atomicAdd(cur + d, 1);
    colsrc[rowp[d] + p] = ei[e];
  }
}

// ---------- fused dual GEMM: xl = h@Wl+bl, xr = h@Wr+br ----------
__global__ __launch_bounds__(256) void dual_gemm(
    const float* __restrict__ h, const float* __restrict__ Wl,
    const float* __restrict__ blv, const float* __restrict__ Wr,
    const float* __restrict__ brv, float* __restrict__ xl, float* __restrict__ xr) {
  __shared__ __align__(16) float Wt[32][256];
  __shared__ __align__(16) float Ht[32][36];
  const int t = threadIdx.x;
  const int row0 = blockIdx.x * 32;
  const int ct = t & 31;
  const int rt = t >> 5;
  float acc[4][8];
#pragma unroll
  for (int i = 0; i < 4; i++)
#pragma unroll
    for (int j = 0; j < 8; j++) acc[i][j] = 0.f;

  const int hr = t >> 3;
  const int hk = (t & 7) << 2;

  for (int k0 = 0; k0 < 128; k0 += 32) {
#pragma unroll
    for (int j = 0; j < 8; j++) {
      int f4 = t + 256 * j;
      int k = f4 >> 6;
      int c4 = (f4 & 63) << 2;
      float4 v;
      if (c4 < 128) v = *(const float4*)(Wl + (size_t)(k0 + k) * 128 + c4);
      else          v = *(const float4*)(Wr + (size_t)(k0 + k) * 128 + (c4 - 128));
      *(float4*)(&Wt[k][c4]) = v;
    }
    float4 hv4 = make_float4(0.f, 0.f, 0.f, 0.f);
    if (row0 + hr < NN) hv4 = *(const float4*)(h + (size_t)(row0 + hr) * DD + k0 + hk);
    Ht[hk + 0][hr] = hv4.x; Ht[hk + 1][hr] = hv4.y;
    Ht[hk + 2][hr] = hv4.z; Ht[hk + 3][hr] = hv4.w;
    __syncthreads();
#pragma unroll
    for (int k = 0; k < 32; k++) {
      float4 w0 = *(const float4*)(&Wt[k][ct << 2]);
      float4 w1 = *(const float4*)(&Wt[k][128 + (ct << 2)]);
      float4 hv = *(const float4*)(&Ht[k][rt << 2]);
      float hs[4] = {hv.x, hv.y, hv.z, hv.w};
#pragma unroll
      for (int i = 0; i < 4; i++) {
        acc[i][0] += hs[i] * w0.x; acc[i][1] += hs[i] * w0.y;
        acc[i][2] += hs[i] * w0.z; acc[i][3] += hs[i] * w0.w;
        acc[i][4] += hs[i] * w1.x; acc[i][5] += hs[i] * w1.y;
        acc[i][6] += hs[i] * w1.z; acc[i][7] += hs[i] * w1.w;
      }
    }
    __syncthreads();
  }
  float4 bl4 = *(const float4*)(blv + (ct << 2));
  float4 br4 = *(const float4*)(brv + (ct << 2));
#pragma unroll
  for (int i = 0; i < 4; i++) {
    int row = row0 + (rt << 2) + i;
    if (row < NN) {
      float4 o0 = make_float4(acc[i][0] + bl4.x, acc[i][1] + bl4.y,
                              acc[i][2] + bl4.z, acc[i][3] + bl4.w);
      float4 o1 = make_float4(acc[i][4] + br4.x, acc[i][5] + br4.y,
                              acc[i][6] + br4.z, acc[i][7] + br4.w);
      *(float4*)(xl + (size_t)row * DD + (ct << 2)) = o0;
      *(float4*)(xr + (size_t)row * DD + (ct << 2)) = o1;
    }
  }
}

// ---------- fused: edge scores + online segment-softmax + aggregation
//            + bias + LayerNorm + ELU.  One wave per destination node. ----------
__global__ __launch_bounds__(256) void fused_edge_agg(
    const int* __restrict__ rowp, const int* __restrict__ colsrc,
    const float* __restrict__ xl, const float* __restrict__ xr,
    const float* __restrict__ att, const float* __restrict__ bias,
    const float* __restrict__ gam, const float* __restrict__ bet,
    float* __restrict__ out) {
  int node = (blockIdx.x * 256 + threadIdx.x) >> 6;
  if (node >= NN) return;
  int lane = threadIdx.x & 63;
  int c = lane << 1;                 // dims c, c+1 (head = lane>>4)
  float2 xrv = *(const float2*)(xr + (size_t)node * DD + c);
  float2 atv = *(const float2*)(att + c);
  int j0 = rowp[node], j1 = rowp[node + 1];

  float m = -INFINITY, den = 0.f, ax = 0.f, ay = 0.f;

  // software-pipelined gather loop with online softmax
  float2 xvN = make_float2(0.f, 0.f);
  if (j0 < j1) {
    int s = colsrc[j0];
    xvN = *(const float2*)(xl + (size_t)s * DD + c);
  }
  for (int j = j0; j < j1; j++) {
    float2 xv = xvN;
    if (j + 1 < j1) {
      int s2 = colsrc[j + 1];
      xvN = *(const float2*)(xl + (size_t)s2 * DD + c);
    }
    float vx = xv.x + xrv.x, vy = xv.y + xrv.y;
    vx = vx > 0.f ? vx : 0.2f * vx;          // leaky_relu NEG=0.2
    vy = vy > 0.f ? vy : 0.2f * vy;
    float p = vx * atv.x + vy * atv.y;
    p += __shfl_xor(p, 1);
    p += __shfl_xor(p, 2);
    p += __shfl_xor(p, 4);
    p += __shfl_xor(p, 8);                   // per-head (16-lane) total, all lanes
    float mn = fmaxf(m, p);
    float sc = __expf(m - mn);               // 1 if m>=p; 0 on first edge (m=-inf)
    float w  = __expf(p - mn);
    den = den * sc + w;
    ax  = ax * sc + w * xv.x;
    ay  = ay * sc + w * xv.y;
    m = mn;
  }

  float inv = 1.f / (den + 1e-16f);
  float vx = ax * inv + bias[c];
  float vy = ay * inv + bias[c + 1];
  float s1 = vx + vy, s2 = vx * vx + vy * vy;
#pragma unroll
  for (int o = 1; o < 64; o <<= 1) { s1 += __shfl_xor(s1, o); s2 += __shfl_xor(s2, o); }
  float mean = s1 * (1.f / 128.f);
  float var = s2 * (1.f / 128.f) - mean * mean;
  float rstd = rsqrtf(var + 1e-5f);
  float nx = (vx - mean) * rstd * gam[c] + bet[c];
  float ny = (vy - mean) * rstd * gam[c + 1] + bet[c + 1];
  out[(size_t)node * DD + c]     = nx > 0.f ? nx : expf(nx) - 1.f;
  out[(size_t)node * DD + c + 1] = ny > 0.f ? ny : expf(ny) - 1.f;
}

extern "C" void kernel_launch(void* const* d_in, const int* in_sizes, int n_in,
                              void* d_out, int out_size, void* d_ws, size_t ws_size,
                              hipStream_t stream) {
  const float* x  = (const float*)d_in[0];
  const int*   ei = (const int*)d_in[1];
  const float* Wl[2]   = {(const float*)d_in[2],  (const float*)d_in[10]};
  const float* bl[2]   = {(const float*)d_in[3],  (const float*)d_in[11]};
  const float* Wr[2]   = {(const float*)d_in[4],  (const float*)d_in[12]};
  const float* br[2]   = {(const float*)d_in[5],  (const float*)d_in[13]};
  const float* att[2]  = {(const float*)d_in[6],  (const float*)d_in[14]};
  const float* bias[2] = {(const float*)d_in[7],  (const float*)d_in[15]};
  const float* gam[2]  = {(const float*)d_in[8],  (const float*)d_in[16]};
  const float* bet[2]  = {(const float*)d_in[9],  (const float*)d_in[17]};
  float* out = (float*)d_out;

  char* w = (char*)d_ws;
  auto carve = [&](size_t bytes) {
    char* p = w;
    w += (bytes + 255) & ~(size_t)255;
    return p;
  };
  float* xl     = (float*)carve((size_t)NN * DD * 4);
  float* xr     = (float*)carve((size_t)NN * DD * 4);
  int*   deg    = (int*)carve((size_t)NN * 4);
  int*   cur    = (int*)carve((size_t)NN * 4);
  int*   rowp   = (int*)carve((size_t)(NN + 1) * 4);
  int*   colsrc = (int*)carve((size_t)NE * 4);
  float* hmid   = (float*)carve((size_t)NN * DD * 4);

  // CSR build (recomputed every call — deterministic, no cross-call state)
  hipMemsetAsync(deg, 0, (size_t)NN * 4, stream);
  hipMemsetAsync(cur, 0, (size_t)NN * 4, stream);
  count_deg<<<(NE + 255) / 256, 256, 0, stream>>>(ei, deg);
  scan_deg<<<1, 1024, 0, stream>>>(deg, rowp);
  scatter_src<<<(NE + 255) / 256, 256, 0, stream>>>(ei, rowp, cur, colsrc);

  for (int l = 0; l < 2; l++) {
    const float* hin = l ? hmid : x;
    float* hout = l ? out : hmid;
    dual_gemm<<<(NN + 31) / 32, 256, 0, stream>>>(hin, Wl[l], bl[l], Wr[l], br[l], xl, xr);
    fused_edge_agg<<<(NN * 64 + 255) / 256, 256, 0, stream>>>(
        rowp, colsrc, xl, xr, att[l], bias[l], gam[l], bet[l], hout);
  }
}

// Round 6
// 423.638 us; speedup vs baseline: 1.8011x; 1.0392x over previous
//
#include <hip/hip_runtime.h>

#define NN 50000
#define NE 600000
#define DD 128
#define NH 4

// ---------- CSR build ----------
__global__ void count_deg(const int* __restrict__ ei, int* __restrict__ deg) {
  int e = blockIdx.x * 256 + threadIdx.x;
  if (e < NE) atomicAdd(deg + ei[NE + e], 1);
}

__global__ void scan_deg(const int* __restrict__ deg, int* __restrict__ rowp) {
  __shared__ int buf[1024];
  __shared__ int carry;
  int t = threadIdx.x;
  if (t == 0) carry = 0;
  __syncthreads();
  for (int base = 0; base < NN; base += 1024) {
    int i = base + t;
    int v = (i < NN) ? deg[i] : 0;
    buf[t] = v;
    __syncthreads();
    for (int o = 1; o < 1024; o <<= 1) {
      int add = (t >= o) ? buf[t - o] : 0;
      __syncthreads();
      buf[t] += add;
      __syncthreads();
    }
    int incl = buf[t];
    if (i < NN) rowp[i] = carry + incl - v;  // exclusive scan + chunk carry
    __syncthreads();
    if (t == 1023) carry += incl;
    __syncthreads();
  }
  if (t == 0) rowp[NN] = carry;
}

// store SOURCE node id directly
__global__ void scatter_src(const int* __restrict__ ei, const int* __restrict__ rowp,
                            int* __restrict__ cur, int* __restrict__ colsrc) {
  int e = blockIdx.x * 256 + threadIdx.x;
  if (e < NE) {
    int d = ei[NE + e];
    int p = atomicAdd(cur + d, 1);
    colsrc[rowp[d] + p] = ei[e];
  }
}

// ---------- fused dual GEMM: xl = h@Wl+bl, xr = h@Wr+br ----------
__global__ __launch_bounds__(256) void dual_gemm(
    const float* __restrict__ h, const float* __restrict__ Wl,
    const float* __restrict__ blv, const float* __restrict__ Wr,
    const float* __restrict__ brv, float* __restrict__ xl, float* __restrict__ xr) {
  __shared__ __align__(16) float Wt[32][256];
  __shared__ __align__(16) float Ht[32][36];
  const int t = threadIdx.x;
  const int row0 = blockIdx.x * 32;
  const int ct = t & 31;
  const int rt = t >> 5;
  float acc[4][8];
#pragma unroll
  for (int i = 0; i < 4; i++)
#pragma unroll
    for (int j = 0; j < 8; j++) acc[i][j] = 0.f;

  const int hr = t >> 3;
  const int hk = (t & 7) << 2;

  for (int k0 = 0; k0 < 128; k0 += 32) {
#pragma unroll
    for (int j = 0; j < 8; j++) {
      int f4 = t + 256 * j;
      int k = f4 >> 6;
      int c4 = (f4 & 63) << 2;
      float4 v;
      if (c4 < 128) v = *(const float4*)(Wl + (size_t)(k0 + k) * 128 + c4);
      else          v = *(const float4*)(Wr + (size_t)(k0 + k) * 128 + (c4 - 128));
      *(float4*)(&Wt[k][c4]) = v;
    }
    float4 hv4 = make_float4(0.f, 0.f, 0.f, 0.f);
    if (row0 + hr < NN) hv4 = *(const float4*)(h + (size_t)(row0 + hr) * DD + k0 + hk);
    Ht[hk + 0][hr] = hv4.x; Ht[hk + 1][hr] = hv4.y;
    Ht[hk + 2][hr] = hv4.z; Ht[hk + 3][hr] = hv4.w;
    __syncthreads();
#pragma unroll
    for (int k = 0; k < 32; k++) {
      float4 w0 = *(const float4*)(&Wt[k][ct << 2]);
      float4 w1 = *(const float4*)(&Wt[k][128 + (ct << 2)]);
      float4 hv = *(const float4*)(&Ht[k][rt << 2]);
      float hs[4] = {hv.x, hv.y, hv.z, hv.w};
#pragma unroll
      for (int i = 0; i < 4; i++) {
        acc[i][0] += hs[i] * w0.x; acc[i][1] += hs[i] * w0.y;
        acc[i][2] += hs[i] * w0.z; acc[i][3] += hs[i] * w0.w;
        acc[i][4] += hs[i] * w1.x; acc[i][5] += hs[i] * w1.y;
        acc[i][6] += hs[i] * w1.z; acc[i][7] += hs[i] * w1.w;
      }
    }
    __syncthreads();
  }
  float4 bl4 = *(const float4*)(blv + (ct << 2));
  float4 br4 = *(const float4*)(brv + (ct << 2));
#pragma unroll
  for (int i = 0; i < 4; i++) {
    int row = row0 + (rt << 2) + i;
    if (row < NN) {
      float4 o0 = make_float4(acc[i][0] + bl4.x, acc[i][1] + bl4.y,
                              acc[i][2] + bl4.z, acc[i][3] + bl4.w);
      float4 o1 = make_float4(acc[i][4] + br4.x, acc[i][5] + br4.y,
                              acc[i][6] + br4.z, acc[i][7] + br4.w);
      *(float4*)(xl + (size_t)row * DD + (ct << 2)) = o0;
      *(float4*)(xr + (size_t)row * DD + (ct << 2)) = o1;
    }
  }
}

// ---------- fused edge path, chunk-4 online softmax ----------
// One wave per destination node. Per 4-edge chunk: 4 gathers issued together
// (4-deep MLP), 4 independent score/shuffle chains, ONE softmax merge.
__global__ __launch_bounds__(256) void fused_edge_agg(
    const int* __restrict__ rowp, const int* __restrict__ colsrc,
    const float* __restrict__ xl, const float* __restrict__ xr,
    const float* __restrict__ att, const float* __restrict__ bias,
    const float* __restrict__ gam, const float* __restrict__ bet,
    float* __restrict__ out) {
  int node = (blockIdx.x * 256 + threadIdx.x) >> 6;
  if (node >= NN) return;
  int lane = threadIdx.x & 63;
  int c = lane << 1;                 // dims c, c+1 (head = lane>>4)
  float2 xrv = *(const float2*)(xr + (size_t)node * DD + c);
  float2 atv = *(const float2*)(att + c);
  int j0 = rowp[node], j1 = rowp[node + 1];

  float m = -INFINITY, den = 0.f, ax = 0.f, ay = 0.f;

  for (int j = j0; j < j1; j += 4) {
    int n = j1 - j; if (n > 4) n = 4;
    float2 xv[4];
    float p[4];
#pragma unroll
    for (int k = 0; k < 4; k++) { xv[k] = make_float2(0.f, 0.f); p[k] = -INFINITY; }
    // issue all gathers first (memory-level parallelism)
#pragma unroll
    for (int k = 0; k < 4; k++) {
      if (k < n) {
        int s = colsrc[j + k];
        xv[k] = *(const float2*)(xl + (size_t)s * DD + c);
      }
    }
    // 4 independent score chains (shuffles pipeline across chains)
#pragma unroll
    for (int k = 0; k < 4; k++) {
      if (k < n) {
        float vx = xv[k].x + xrv.x, vy = xv[k].y + xrv.y;
        vx = vx > 0.f ? vx : 0.2f * vx;      // leaky_relu NEG=0.2
        vy = vy > 0.f ? vy : 0.2f * vy;
        float pp = vx * atv.x + vy * atv.y;
        pp += __shfl_xor(pp, 1);
        pp += __shfl_xor(pp, 2);
        pp += __shfl_xor(pp, 4);
        pp += __shfl_xor(pp, 8);             // per-head (16-lane) total
        p[k] = pp;
      }
    }
    // chunk-local softmax combine (p[k] = -inf for pads -> weight 0)
    float m4 = fmaxf(fmaxf(p[0], p[1]), fmaxf(p[2], p[3]));  // finite (n>=1)
    float w0 = __expf(p[0] - m4), w1 = __expf(p[1] - m4);
    float w2 = __expf(p[2] - m4), w3 = __expf(p[3] - m4);
    float sw = (w0 + w1) + (w2 + w3);
    float sx = (w0 * xv[0].x + w1 * xv[1].x) + (w2 * xv[2].x + w3 * xv[3].x);
    float sy = (w0 * xv[0].y + w1 * xv[1].y) + (w2 * xv[2].y + w3 * xv[3].y);
    // single online merge per chunk
    float mn = fmaxf(m, m4);
    float a = __expf(m - mn);                // 0 on first chunk (m=-inf)
    float b = __expf(m4 - mn);
    den = den * a + sw * b;
    ax  = ax * a + sx * b;
    ay  = ay * a + sy * b;
    m = mn;
  }

  float inv = 1.f / (den + 1e-16f);
  float vx = ax * inv + bias[c];
  float vy = ay * inv + bias[c + 1];
  float s1 = vx + vy, s2 = vx * vx + vy * vy;
#pragma unroll
  for (int o = 1; o < 64; o <<= 1) { s1 += __shfl_xor(s1, o); s2 += __shfl_xor(s2, o); }
  float mean = s1 * (1.f / 128.f);
  float var = s2 * (1.f / 128.f) - mean * mean;
  float rstd = rsqrtf(var + 1e-5f);
  float nx = (vx - mean) * rstd * gam[c] + bet[c];
  float ny = (vy - mean) * rstd * gam[c + 1] + bet[c + 1];
  out[(size_t)node * DD + c]     = nx > 0.f ? nx : expf(nx) - 1.f;
  out[(size_t)node * DD + c + 1] = ny > 0.f ? ny : expf(ny) - 1.f;
}

extern "C" void kernel_launch(void* const* d_in, const int* in_sizes, int n_in,
                              void* d_out, int out_size, void* d_ws, size_t ws_size,
                              hipStream_t stream) {
  const float* x  = (const float*)d_in[0];
  const int*   ei = (const int*)d_in[1];
  const float* Wl[2]   = {(const float*)d_in[2],  (const float*)d_in[10]};
  const float* bl[2]   = {(const float*)d_in[3],  (const float*)d_in[11]};
  const float* Wr[2]   = {(const float*)d_in[4],  (const float*)d_in[12]};
  const float* br[2]   = {(const float*)d_in[5],  (const float*)d_in[13]};
  const float* att[2]  = {(const float*)d_in[6],  (const float*)d_in[14]};
  const float* bias[2] = {(const float*)d_in[7],  (const float*)d_in[15]};
  const float* gam[2]  = {(const float*)d_in[8],  (const float*)d_in[16]};
  const float* bet[2]  = {(const float*)d_in[9],  (const float*)d_in[17]};
  float* out = (float*)d_out;

  char* w = (char*)d_ws;
  auto carve = [&](size_t bytes) {
    char* p = w;
    w += (bytes + 255) & ~(size_t)255;
    return p;
  };
  float* xl     = (float*)carve((size_t)NN * DD * 4);
  float* xr     = (float*)carve((size_t)NN * DD * 4);
  int*   deg    = (int*)carve((size_t)NN * 4);
  int*   cur    = (int*)carve((size_t)NN * 4);
  int*   rowp   = (int*)carve((size_t)(NN + 1) * 4);
  int*   colsrc = (int*)carve((size_t)NE * 4);
  float* hmid   = (float*)carve((size_t)NN * DD * 4);

  // CSR build (recomputed every call — deterministic, no cross-call state)
  hipMemsetAsync(deg, 0, (size_t)NN * 4, stream);
  hipMemsetAsync(cur, 0, (size_t)NN * 4, stream);
  count_deg<<<(NE + 255) / 256, 256, 0, stream>>>(ei, deg);
  scan_deg<<<1, 1024, 0, stream>>>(deg, rowp);
  scatter_src<<<(NE + 255) / 256, 256, 0, stream>>>(ei, rowp, cur, colsrc);

  for (int l = 0; l < 2; l++) {
    const float* hin = l ? hmid : x;
    float* hout = l ? out : hmid;
    dual_gemm<<<(NN + 31) / 32, 256, 0, stream>>>(hin, Wl[l], bl[l], Wr[l], br[l], xl, xr);
    fused_edge_agg<<<(NN * 64 + 255) / 256, 256, 0, stream>>>(
        rowp, colsrc, xl, xr, att[l], bias[l], gam[l], bet[l], hout);
  }
}

// Round 7
// 344.650 us; speedup vs baseline: 2.2139x; 1.2292x over previous
//
#include <hip/hip_runtime.h>

#define NN 50000
#define NE 600000
#define DD 128
#define NH 4

#define SCAN_T 512
#define SCAN_B ((NN + SCAN_T - 1) / SCAN_T)   // 98 blocks

// ---------- CSR build ----------
__global__ void count_deg(const int* __restrict__ ei, int* __restrict__ deg) {
  int e = blockIdx.x * 256 + threadIdx.x;
  if (e < NE) atomicAdd(deg + ei[NE + e], 1);
}

// phase 1: per-block exclusive scan of a 512-tile; block total -> bsum[b]
__global__ __launch_bounds__(SCAN_T) void scan_partial(
    const int* __restrict__ deg, int* __restrict__ rowp, int* __restrict__ bsum) {
  __shared__ int buf[SCAN_T];
  int b = blockIdx.x, t = threadIdx.x;
  int i = b * SCAN_T + t;
  int v = (i < NN) ? deg[i] : 0;
  buf[t] = v;
  __syncthreads();
  for (int o = 1; o < SCAN_T; o <<= 1) {
    int add = (t >= o) ? buf[t - o] : 0;
    __syncthreads();
    buf[t] += add;
    __syncthreads();
  }
  if (i < NN) rowp[i] = buf[t] - v;            // tile-local exclusive
  if (t == SCAN_T - 1) bsum[b] = buf[t];       // tile total
}

// phase 2: scan the 98 block totals (one small block)
__global__ __launch_bounds__(128) void scan_bsums(
    int* __restrict__ bsum, int* __restrict__ boff, int* __restrict__ rowp) {
  __shared__ int buf[128];
  int t = threadIdx.x;
  int v = (t < SCAN_B) ? bsum[t] : 0;
  buf[t] = v;
  __syncthreads();
  for (int o = 1; o < 128; o <<= 1) {
    int add = (t >= o) ? buf[t - o] : 0;
    __syncthreads();
    buf[t] += add;
    __syncthreads();
  }
  if (t < SCAN_B) boff[t] = buf[t] - v;        // exclusive
  if (t == 127) rowp[NN] = buf[t];             // grand total (== NE)
}

// phase 3: add block offsets
__global__ __launch_bounds__(SCAN_T) void scan_add(
    int* __restrict__ rowp, const int* __restrict__ boff) {
  int b = blockIdx.x, t = threadIdx.x;
  int i = b * SCAN_T + t;
  if (i < NN) rowp[i] += boff[b];
}

// store SOURCE node id directly
__global__ void scatter_src(const int* __restrict__ ei, const int* __restrict__ rowp,
                            int* __restrict__ cur, int* __restrict__ colsrc) {
  int e = blockIdx.x * 256 + threadIdx.x;
  if (e < NE) {
    int d = ei[NE + e];
    int p = atomicAdd(cur + d, 1);
    colsrc[rowp[d] + p] = ei[e];
  }
}

// ---------- fused dual GEMM: xl = h@Wl+bl, xr = h@Wr+br ----------
__global__ __launch_bounds__(256) void dual_gemm(
    const float* __restrict__ h, const float* __restrict__ Wl,
    const float* __restrict__ blv, const float* __restrict__ Wr,
    const float* __restrict__ brv, float* __restrict__ xl, float* __restrict__ xr) {
  __shared__ __align__(16) float Wt[32][256];
  __shared__ __align__(16) float Ht[32][36];
  const int t = threadIdx.x;
  const int row0 = blockIdx.x * 32;
  const int ct = t & 31;
  const int rt = t >> 5;
  float acc[4][8];
#pragma unroll
  for (int i = 0; i < 4; i++)
#pragma unroll
    for (int j = 0; j < 8; j++) acc[i][j] = 0.f;

  const int hr = t >> 3;
  const int hk = (t & 7) << 2;

  for (int k0 = 0; k0 < 128; k0 += 32) {
#pragma unroll
    for (int j = 0; j < 8; j++) {
      int f4 = t + 256 * j;
      int k = f4 >> 6;
      int c4 = (f4 & 63) << 2;
      float4 v;
      if (c4 < 128) v = *(const float4*)(Wl + (size_t)(k0 + k) * 128 + c4);
      else          v = *(const float4*)(Wr + (size_t)(k0 + k) * 128 + (c4 - 128));
      *(float4*)(&Wt[k][c4]) = v;
    }
    float4 hv4 = make_float4(0.f, 0.f, 0.f, 0.f);
    if (row0 + hr < NN) hv4 = *(const float4*)(h + (size_t)(row0 + hr) * DD + k0 + hk);
    Ht[hk + 0][hr] = hv4.x; Ht[hk + 1][hr] = hv4.y;
    Ht[hk + 2][hr] = hv4.z; Ht[hk + 3][hr] = hv4.w;
    __syncthreads();
#pragma unroll
    for (int k = 0; k < 32; k++) {
      float4 w0 = *(const float4*)(&Wt[k][ct << 2]);
      float4 w1 = *(const float4*)(&Wt[k][128 + (ct << 2)]);
      float4 hv = *(const float4*)(&Ht[k][rt << 2]);
      float hs[4] = {hv.x, hv.y, hv.z, hv.w};
#pragma unroll
      for (int i = 0; i < 4; i++) {
        acc[i][0] += hs[i] * w0.x; acc[i][1] += hs[i] * w0.y;
        acc[i][2] += hs[i] * w0.z; acc[i][3] += hs[i] * w0.w;
        acc[i][4] += hs[i] * w1.x; acc[i][5] += hs[i] * w1.y;
        acc[i][6] += hs[i] * w1.z; acc[i][7] += hs[i] * w1.w;
      }
    }
    __syncthreads();
  }
  float4 bl4 = *(const float4*)(blv + (ct << 2));
  float4 br4 = *(const float4*)(brv + (ct << 2));
#pragma unroll
  for (int i = 0; i < 4; i++) {
    int row = row0 + (rt << 2) + i;
    if (row < NN) {
      float4 o0 = make_float4(acc[i][0] + bl4.x, acc[i][1] + bl4.y,
                              acc[i][2] + bl4.z, acc[i][3] + bl4.w);
      float4 o1 = make_float4(acc[i][4] + br4.x, acc[i][5] + br4.y,
                              acc[i][6] + br4.z, acc[i][7] + br4.w);
      *(float4*)(xl + (size_t)row * DD + (ct << 2)) = o0;
      *(float4*)(xr + (size_t)row * DD + (ct << 2)) = o1;
    }
  }
}

// ---------- fused edge path, chunk-4 online softmax ----------
__global__ __launch_bounds__(256) void fused_edge_agg(
    const int* __restrict__ rowp, const int* __restrict__ colsrc,
    const float* __restrict__ xl, const float* __restrict__ xr,
    const float* __restrict__ att, const float* __restrict__ bias,
    const float* __restrict__ gam, const float* __restrict__ bet,
    float* __restrict__ out) {
  int node = (blockIdx.x * 256 + threadIdx.x) >> 6;
  if (node >= NN) return;
  int lane = threadIdx.x & 63;
  int c = lane << 1;                 // dims c, c+1 (head = lane>>4)
  float2 xrv = *(const float2*)(xr + (size_t)node * DD + c);
  float2 atv = *(const float2*)(att + c);
  int j0 = rowp[node], j1 = rowp[node + 1];

  float m = -INFINITY, den = 0.f, ax = 0.f, ay = 0.f;

  for (int j = j0; j < j1; j += 4) {
    int n = j1 - j; if (n > 4) n = 4;
    float2 xv[4];
    float p[4];
#pragma unroll
    for (int k = 0; k < 4; k++) { xv[k] = make_float2(0.f, 0.f); p[k] = -INFINITY; }
#pragma unroll
    for (int k = 0; k < 4; k++) {
      if (k < n) {
        int s = colsrc[j + k];
        xv[k] = *(const float2*)(xl + (size_t)s * DD + c);
      }
    }
#pragma unroll
    for (int k = 0; k < 4; k++) {
      if (k < n) {
        float vx = xv[k].x + xrv.x, vy = xv[k].y + xrv.y;
        vx = vx > 0.f ? vx : 0.2f * vx;      // leaky_relu NEG=0.2
        vy = vy > 0.f ? vy : 0.2f * vy;
        float pp = vx * atv.x + vy * atv.y;
        pp += __shfl_xor(pp, 1);
        pp += __shfl_xor(pp, 2);
        pp += __shfl_xor(pp, 4);
        pp += __shfl_xor(pp, 8);             // per-head (16-lane) total
        p[k] = pp;
      }
    }
    float m4 = fmaxf(fmaxf(p[0], p[1]), fmaxf(p[2], p[3]));
    float w0 = __expf(p[0] - m4), w1 = __expf(p[1] - m4);
    float w2 = __expf(p[2] - m4), w3 = __expf(p[3] - m4);
    float sw = (w0 + w1) + (w2 + w3);
    float sx = (w0 * xv[0].x + w1 * xv[1].x) + (w2 * xv[2].x + w3 * xv[3].x);
    float sy = (w0 * xv[0].y + w1 * xv[1].y) + (w2 * xv[2].y + w3 * xv[3].y);
    float mn = fmaxf(m, m4);
    float a = __expf(m - mn);
    float b = __expf(m4 - mn);
    den = den * a + sw * b;
    ax  = ax * a + sx * b;
    ay  = ay * a + sy * b;
    m = mn;
  }

  float inv = 1.f / (den + 1e-16f);
  float vx = ax * inv + bias[c];
  float vy = ay * inv + bias[c + 1];
  float s1 = vx + vy, s2 = vx * vx + vy * vy;
#pragma unroll
  for (int o = 1; o < 64; o <<= 1) { s1 += __shfl_xor(s1, o); s2 += __shfl_xor(s2, o); }
  float mean = s1 * (1.f / 128.f);
  float var = s2 * (1.f / 128.f) - mean * mean;
  float rstd = rsqrtf(var + 1e-5f);
  float nx = (vx - mean) * rstd * gam[c] + bet[c];
  float ny = (vy - mean) * rstd * gam[c + 1] + bet[c + 1];
  out[(size_t)node * DD + c]     = nx > 0.f ? nx : expf(nx) - 1.f;
  out[(size_t)node * DD + c + 1] = ny > 0.f ? ny : expf(ny) - 1.f;
}

extern "C" void kernel_launch(void* const* d_in, const int* in_sizes, int n_in,
                              void* d_out, int out_size, void* d_ws, size_t ws_size,
                              hipStream_t stream) {
  const float* x  = (const float*)d_in[0];
  const int*   ei = (const int*)d_in[1];
  const float* Wl[2]   = {(const float*)d_in[2],  (const float*)d_in[10]};
  const float* bl[2]   = {(const float*)d_in[3],  (const float*)d_in[11]};
  const float* Wr[2]   = {(const float*)d_in[4],  (const float*)d_in[12]};
  const float* br[2]   = {(const float*)d_in[5],  (const float*)d_in[13]};
  const float* att[2]  = {(const float*)d_in[6],  (const float*)d_in[14]};
  const float* bias[2] = {(const float*)d_in[7],  (const float*)d_in[15]};
  const float* gam[2]  = {(const float*)d_in[8],  (const float*)d_in[16]};
  const float* bet[2]  = {(const float*)d_in[9],  (const float*)d_in[17]};
  float* out = (float*)d_out;

  char* w = (char*)d_ws;
  auto carve = [&](size_t bytes) {
    char* p = w;
    w += (bytes + 255) & ~(size_t)255;
    return p;
  };
  float* xl     = (float*)carve((size_t)NN * DD * 4);
  float* xr     = (float*)carve((size_t)NN * DD * 4);
  int*   deg    = (int*)carve((size_t)NN * 4);
  int*   cur    = (int*)carve((size_t)NN * 4);
  int*   rowp   = (int*)carve((size_t)(NN + 1) * 4);
  int*   colsrc = (int*)carve((size_t)NE * 4);
  int*   bsum   = (int*)carve((size_t)SCAN_B * 4);
  int*   boff   = (int*)carve((size_t)SCAN_B * 4);
  float* hmid   = (float*)carve((size_t)NN * DD * 4);

  // CSR build (recomputed every call — deterministic, no cross-call state)
  hipMemsetAsync(deg, 0, (size_t)NN * 4, stream);
  hipMemsetAsync(cur, 0, (size_t)NN * 4, stream);
  count_deg<<<(NE + 255) / 256, 256, 0, stream>>>(ei, deg);
  scan_partial<<<SCAN_B, SCAN_T, 0, stream>>>(deg, rowp, bsum);
  scan_bsums<<<1, 128, 0, stream>>>(bsum, boff, rowp);
  scan_add<<<SCAN_B, SCAN_T, 0, stream>>>(rowp, boff);
  scatter_src<<<(NE + 255) / 256, 256, 0, stream>>>(ei, rowp, cur, colsrc);

  for (int l = 0; l < 2; l++) {
    const float* hin = l ? hmid : x;
    float* hout = l ? out : hmid;
    dual_gemm<<<(NN + 31) / 32, 256, 0, stream>>>(hin, Wl[l], bl[l], Wr[l], br[l], xl, xr);
    fused_edge_agg<<<(NN * 64 + 255) / 256, 256, 0, stream>>>(
        rowp, colsrc, xl, xr, att[l], bias[l], gam[l], bet[l], hout);
  }
}